// Round 2
// baseline (473.405 us; speedup 1.0000x reference)
//
#include <hip/hip_runtime.h>

#define NN 50000
#define NE 1600000
#define DIM 256
#define OUTD 64
#define ALPHA 0.2f
#define SCAN_BLOCKS ((NN + 255) / 256)  // 196

// ---------------------------------------------------------------------------
// h = x @ W  (fp32), plus per-node logit partials s1 = h.a[:64], s2 = h.a[64:]
// Block = 256 threads = 4 waves; block handles 16 rows; wave w handles rows
// {w, w+4, w+8, w+12}; lane = output column. W staged in LDS ([k][o]; lanes
// read 64 consecutive words -> 2-way bank alias = free on CDNA4). x rows are
// wave-uniform float4 loads (SGPR address after readfirstlane -> s_load path).
// ---------------------------------------------------------------------------
__global__ __launch_bounds__(256) void gemm_h_kernel(
    const float* __restrict__ x, const float* __restrict__ W,
    const float* __restrict__ a, float* __restrict__ h,
    float* __restrict__ s1, float* __restrict__ s2)
{
  __shared__ float Wl[DIM][OUTD];  // 64 KB
  const int t = threadIdx.x;
  for (int i = t; i < DIM * OUTD; i += 256) Wl[i >> 6][i & 63] = W[i];
  __syncthreads();

  const int o = t & 63;
  const int rsub = __builtin_amdgcn_readfirstlane(t >> 6);  // wave id, SGPR
  const int row0 = blockIdx.x * 16;

  const float4* xr0 = (const float4*)(x + (size_t)(row0 + rsub) * DIM);
  const float4* xr1 = xr0 + DIM;      // +4 rows  (4*DIM floats = DIM float4)
  const float4* xr2 = xr0 + 2 * DIM;  // +8 rows
  const float4* xr3 = xr0 + 3 * DIM;  // +12 rows

  float acc0 = 0.f, acc1 = 0.f, acc2 = 0.f, acc3 = 0.f;
#pragma unroll 2
  for (int k4 = 0; k4 < DIM / 4; ++k4) {
    const float4 u0 = xr0[k4], u1 = xr1[k4], u2 = xr2[k4], u3 = xr3[k4];
    const float w0 = Wl[4 * k4 + 0][o];
    const float w1 = Wl[4 * k4 + 1][o];
    const float w2 = Wl[4 * k4 + 2][o];
    const float w3 = Wl[4 * k4 + 3][o];
    acc0 = fmaf(u0.x, w0, acc0); acc0 = fmaf(u0.y, w1, acc0);
    acc0 = fmaf(u0.z, w2, acc0); acc0 = fmaf(u0.w, w3, acc0);
    acc1 = fmaf(u1.x, w0, acc1); acc1 = fmaf(u1.y, w1, acc1);
    acc1 = fmaf(u1.z, w2, acc1); acc1 = fmaf(u1.w, w3, acc1);
    acc2 = fmaf(u2.x, w0, acc2); acc2 = fmaf(u2.y, w1, acc2);
    acc2 = fmaf(u2.z, w2, acc2); acc2 = fmaf(u2.w, w3, acc2);
    acc3 = fmaf(u3.x, w0, acc3); acc3 = fmaf(u3.y, w1, acc3);
    acc3 = fmaf(u3.z, w2, acc3); acc3 = fmaf(u3.w, w3, acc3);
  }

  const float a1 = a[o];
  const float a2 = a[OUTD + o];
  float accs[4] = {acc0, acc1, acc2, acc3};
#pragma unroll
  for (int j = 0; j < 4; ++j) {
    const int r = row0 + rsub + 4 * j;
    h[(size_t)r * OUTD + o] = accs[j];
    float p1 = accs[j] * a1;
    float p2 = accs[j] * a2;
    for (int off = 32; off > 0; off >>= 1) {
      p1 += __shfl_xor(p1, off);
      p2 += __shfl_xor(p2, off);
    }
    if (o == 0) { s1[r] = p1; s2[r] = p2; }
  }
}

// ---------------------------------------------------------------------------
// CSR construction: degree count, 3-kernel exclusive scan, bucket scatter.
// ---------------------------------------------------------------------------
__global__ __launch_bounds__(256) void deg_kernel(const int* __restrict__ src,
                                                  int* __restrict__ deg) {
  const int e = blockIdx.x * 256 + threadIdx.x;
  if (e < NE) atomicAdd(&deg[src[e]], 1);
}

__global__ __launch_bounds__(256) void scan1_kernel(const int* __restrict__ deg,
                                                    int* __restrict__ pre,
                                                    int* __restrict__ bsum) {
  __shared__ int tmp[256];
  const int t = threadIdx.x;
  const int g = blockIdx.x * 256 + t;
  const int v = (g < NN) ? deg[g] : 0;
  int xv = v;
  tmp[t] = v;
  __syncthreads();
  for (int off = 1; off < 256; off <<= 1) {
    const int y = (t >= off) ? tmp[t - off] : 0;
    __syncthreads();
    xv += y;
    tmp[t] = xv;
    __syncthreads();
  }
  if (g < NN) pre[g] = xv - v;          // exclusive within block
  if (t == 255) bsum[blockIdx.x] = xv;  // block total
}

__global__ __launch_bounds__(256) void scan2_kernel(int* __restrict__ bsum) {
  __shared__ int tmp[256];
  const int t = threadIdx.x;
  const int v = (t < SCAN_BLOCKS) ? bsum[t] : 0;
  int xv = v;
  tmp[t] = v;
  __syncthreads();
  for (int off = 1; off < 256; off <<= 1) {
    const int y = (t >= off) ? tmp[t - off] : 0;
    __syncthreads();
    xv += y;
    tmp[t] = xv;
    __syncthreads();
  }
  if (t < SCAN_BLOCKS) bsum[t] = xv - v;  // exclusive block offsets
}

__global__ __launch_bounds__(256) void scan3_kernel(int* __restrict__ pre,
                                                    const int* __restrict__ bsum,
                                                    int* __restrict__ cursor) {
  const int g = blockIdx.x * 256 + threadIdx.x;
  if (g < NN) {
    const int val = pre[g] + bsum[blockIdx.x];
    pre[g] = val;     // rowstart
    cursor[g] = val;  // bucket cursor
  }
}

__global__ __launch_bounds__(256) void bucket_kernel(const int* __restrict__ src,
                                                     const int* __restrict__ dst,
                                                     int* __restrict__ cursor,
                                                     int* __restrict__ edst) {
  const int e = blockIdx.x * 256 + threadIdx.x;
  if (e < NE) {
    const int s = src[e];
    const int slot = atomicAdd(&cursor[s], 1);
    edst[slot] = dst[e];
  }
}

// ---------------------------------------------------------------------------
// Aggregation: one wave per node. Lane = output dim. Chunk of 64 edges:
// each lane computes one edge's weight w = exp(-leakyrelu(s1[i]+s2[dst])),
// then readlane-broadcast (dst, w) and every lane does
// acc[lane] += w * h[dst][lane] (coalesced 256B gather). wsum accumulates
// the broadcast w (identical in every lane). No atomics, no LDS.
// ---------------------------------------------------------------------------
__global__ __launch_bounds__(256) void agg_kernel(
    const float* __restrict__ h, const float* __restrict__ s1,
    const float* __restrict__ s2, const int* __restrict__ pre,
    const int* __restrict__ deg, const int* __restrict__ edst,
    float* __restrict__ out)
{
  const int lane = threadIdx.x & 63;
  const int node =
      __builtin_amdgcn_readfirstlane(blockIdx.x * 4 + (threadIdx.x >> 6));
  const int base = pre[node];
  const int cnt = deg[node];
  const float s1i = s1[node];

  float acc = 0.f;
  float wsum = 0.f;
  for (int c = 0; c < cnt; c += 64) {
    const int m = min(64, cnt - c);
    int d = 0;
    float w = 0.f;
    if (lane < m) {
      d = edst[base + c + lane];
      const float logit = s1i + s2[d];
      const float lr = logit > 0.f ? logit : ALPHA * logit;
      w = __expf(-lr);
    }
#pragma unroll 4
    for (int l = 0; l < m; ++l) {
      const int dv = __builtin_amdgcn_readlane(d, l);
      const float wv =
          __uint_as_float(__builtin_amdgcn_readlane(__float_as_uint(w), l));
      acc = fmaf(wv, h[(size_t)dv * OUTD + lane], acc);
      wsum += wv;
    }
  }
  const float val = (cnt > 0) ? (acc / wsum) : 0.f;
  const float r = val > 0.f ? val : (__expf(val) - 1.f);  // elu
  out[(size_t)node * OUTD + lane] = r;
}

// ---------------------------------------------------------------------------
extern "C" void kernel_launch(void* const* d_in, const int* in_sizes, int n_in,
                              void* d_out, int out_size, void* d_ws, size_t ws_size,
                              hipStream_t stream) {
  const float* x = (const float*)d_in[0];
  const int* ei = (const int*)d_in[1];
  const float* W = (const float*)d_in[2];
  const float* a = (const float*)d_in[3];
  float* out = (float*)d_out;

  // workspace layout (~20.2 MB total)
  float* h = (float*)d_ws;              // NN*64 fp32
  float* s1 = h + (size_t)NN * OUTD;    // NN
  float* s2 = s1 + NN;                  // NN
  int* deg = (int*)(s2 + NN);           // NN
  int* pre = deg + NN;                  // NN (rowstart)
  int* bsum = pre + NN;                 // 256
  int* cursor = bsum + 256;             // NN
  int* edst = cursor + NN;              // NE

  const int* src = ei;
  const int* dst = ei + NE;

  hipMemsetAsync(deg, 0, NN * sizeof(int), stream);
  hipLaunchKernelGGL(gemm_h_kernel, dim3(NN / 16), dim3(256), 0, stream,
                     x, W, a, h, s1, s2);
  hipLaunchKernelGGL(deg_kernel, dim3((NE + 255) / 256), dim3(256), 0, stream,
                     src, deg);
  hipLaunchKernelGGL(scan1_kernel, dim3(SCAN_BLOCKS), dim3(256), 0, stream,
                     deg, pre, bsum);
  hipLaunchKernelGGL(scan2_kernel, dim3(1), dim3(256), 0, stream, bsum);
  hipLaunchKernelGGL(scan3_kernel, dim3(SCAN_BLOCKS), dim3(256), 0, stream,
                     pre, bsum, cursor);
  hipLaunchKernelGGL(bucket_kernel, dim3((NE + 255) / 256), dim3(256), 0, stream,
                     src, dst, cursor, edst);
  hipLaunchKernelGGL(agg_kernel, dim3(NN / 4), dim3(256), 0, stream,
                     h, s1, s2, pre, deg, edst, out);
}